// Round 14
// baseline (112.375 us; speedup 1.0000x reference)
//
#include <hip/hip_runtime.h>
#include <hip/hip_bf16.h>
#include <hip/hip_cooperative_groups.h>
#include <math.h>

// ---------------------------------------------------------------------------
// BernNet: out = log_softmax( bern_prop( relu(x@W1+b1)@W2+b2 ) )
// bern_prop in monomial basis (10 matvecs, not 65); trailing-zero fast path:
// graph work in ONE cooperative kernel that exits when a_j==0 for j>=1
// (log_softmax then fused into the MLP epilogue).
// MLP (R13 structure, occupancy-tuned): 64x256 tile, 4 waves, 48KB LDS ->
// 3 blocks/CU (was 2) so cross-block overlap fills the per-K-step vmcnt
// drains (m114 mechanism). Both streams via global_load_lds (VGPR-free DMA
// the compiler cannot sink); A fp32 with source-side XOR swizzle (2-way ->
// free); B fragment-linear (bank-balanced b128). One barrier per K-step.
// h1 kept in a 32KB LDS image; phase-2 h1@W2 with split hi/lo bf16 W2;
// fused log_softmax epilogue on the fast path.
// ---------------------------------------------------------------------------

#define KORD 10

namespace cg = cooperative_groups;

typedef __attribute__((ext_vector_type(8))) short bf16x8;
typedef __attribute__((ext_vector_type(4))) float f32x4;

typedef __attribute__((address_space(1))) const unsigned int* gas_t;
typedef __attribute__((address_space(3))) unsigned int* las_t;

static __device__ __forceinline__ void gll16(const void* g, void* l) {
    // per-lane global addr g; wave-uniform LDS base l; writes l + lane*16
    __builtin_amdgcn_global_load_lds((gas_t)g, (las_t)l, 16, 0, 0);
}

static __device__ __forceinline__ ushort f2bf(float f) {   // RNE
    unsigned u = __float_as_uint(f);
    unsigned r = (u + 0x7fffu + ((u >> 16) & 1u)) >> 16;
    return (ushort)r;
}
static __device__ __forceinline__ float bf2f(ushort h) {
    return __uint_as_float(((unsigned)h) << 16);
}
// truncation pack: low16 = bf16_trunc(a), high16 = bf16_trunc(b)
static __device__ __forceinline__ uint pk2t(float a, float b) {
    return (__float_as_uint(a) >> 16) | (__float_as_uint(b) & 0xffff0000u);
}
static __device__ __forceinline__ bf16x8 mk8(uint a, uint b, uint c, uint d) {
    union { uint4 u; bf16x8 v; } x;
    x.u = make_uint4(a, b, c, d);
    return x.v;
}

// ---- one-time setup: monomial coeffs + weight conversion -------------------
// W1 -> fragment-linear bf16: idx = kt*8192 + col*32 + lg*8 + j  (k=kt*32+lg*8+j)
// W2 -> hi/lo bf16:           idx = ks*2048 + col*32 + lg*8 + j  (k=ks*32+lg*8+j)
__global__ void prep_all(const float* __restrict__ temp,
                         const float* __restrict__ W1, const float* __restrict__ W2,
                         float* __restrict__ acoef, int* __restrict__ flags,
                         ushort* __restrict__ w1b,
                         ushort* __restrict__ w2h, ushort* __restrict__ w2l)
{
    int tid = blockIdx.x * 256 + threadIdx.x;
    if (tid == 0) {
        int C[KORD + 1][KORD + 1];
        for (int n = 0; n <= KORD; ++n) {
            for (int k = 0; k <= KORD; ++k) C[n][k] = 0;
            C[n][0] = 1;
            for (int k = 1; k <= n; ++k)
                C[n][k] = C[n - 1][k - 1] + ((k <= n - 1) ? C[n - 1][k] : 0);
        }
        float a[KORD + 1];
        for (int j = 0; j <= KORD; ++j) a[j] = 0.f;
        for (int m = 0; m <= KORD; ++m) {
            float tm = temp[m];
            tm = tm > 0.f ? tm : 0.f;
            float cm = (float)C[KORD][m] / 1024.0f;
            for (int p = 0; p <= m; ++p)
                for (int q = 0; q <= KORD - m; ++q) {
                    int Mij = ((p & 1) ? -1 : 1) * C[m][p] * C[KORD - m][q];
                    a[p + q] += cm * tm * (float)Mij;
                }
        }
        for (int j = 0; j <= KORD; ++j) acoef[j] = a[j];
        int any = 0;
        for (int j = KORD; j >= 0; --j) {
            if (a[j] != 0.f) any = 1;
            flags[j] = any;
        }
    }
    if (tid < 512 * 256) {
        int j = tid & 7, lg = (tid >> 3) & 3, col = (tid >> 5) & 255, kt = tid >> 13;
        int k = kt * 32 + lg * 8 + j;
        w1b[tid] = f2bf(W1[k * 256 + col]);
    } else if (tid < 512 * 256 + 256 * 64) {
        int t2 = tid - 512 * 256;
        int j = t2 & 7, lg = (t2 >> 3) & 3, col = (t2 >> 5) & 63, ks = t2 >> 11;
        int k = ks * 32 + lg * 8 + j;
        float v = W2[k * 64 + col];
        ushort hi = f2bf(v);
        ushort lo = f2bf(v - bf2f(hi));
        w2h[t2] = hi; w2l[t2] = lo;
    }
}

// ---- fused MLP ------------------------------------------------------------
// 256 thr / 4 waves; tile 64 rows x 256 cols, K=512, BK=32.
// LDS: [0:8K) A0 fp32, [8K:16K) A1, [16K:32K) B0 bf16, [32K:48K) B1;
// h1 image reuses [0:32K). Wave (wm=wid>>1, wn=wid&1) -> 32x128 output.
// A LDS layout: row-major [64 rows][128B], 16B-unit kq pre-swizzled at the
// GLOBAL source: position kq holds floats (kq ^ ((row&3)<<1))*4 .. +3.
__global__ __launch_bounds__(256, 3) void mlp_kernel(
    const float* __restrict__ x,
    const ushort* __restrict__ w1b,
    const ushort* __restrict__ w2h, const ushort* __restrict__ w2l,
    const float* __restrict__ b1, const float* __restrict__ b2,
    float* __restrict__ v0, float* __restrict__ out,
    const float* __restrict__ acoef, const int* __restrict__ flags, int N)
{
    __shared__ __align__(16) char sm[49152];

    const int t    = threadIdx.x;
    const int lane = t & 63;
    const int wid  = t >> 6;        // 0..3
    const int wm   = wid >> 1;      // 0..1 row half (32 rows)
    const int wn   = wid & 1;       // 0..1 col half (128 cols)
    const int l15  = lane & 15;
    const int lg   = lane >> 4;
    const int row0 = blockIdx.x * 64;

    // staging geometry: A call c (c=0,1): lane covers tile-local row
    //   arow_c = wid*16 + c*8 + (lane>>3), position kq = lane&7;
    //   global float = (kq ^ ((arow&3)<<1))*4 + kt*32.
    const int arow0 = wid * 16 + (lane >> 3);
    const int arow1 = arow0 + 8;
    const int akq   = lane & 7;
    int gr0 = row0 + arow0; if (gr0 > N - 1) gr0 = N - 1;
    int gr1 = row0 + arow1; if (gr1 > N - 1) gr1 = N - 1;
    const float* gsA0 = x + (size_t)gr0 * 512 + ((akq ^ ((arow0 & 3) << 1)) << 2);
    const float* gsA1 = x + (size_t)gr1 * 512 + ((akq ^ ((arow1 & 3) << 1)) << 2);
    const char* w1g = (const char*)w1b;
    const int aoff = wid * 2048;            // wave's 2KB A slice (2 calls x 1KB)
    const int boff = wid * 4096;            // wave's 4KB B slice (4 calls x 1KB)

    f32x4 acc[2][8];
#pragma unroll
    for (int i = 0; i < 2; ++i)
#pragma unroll
        for (int j = 0; j < 8; ++j) acc[i][j] = (f32x4)0.f;

    // ---- prologue: stage kt=0 into buf0 ----
    gll16(gsA0, sm + aoff);
    gll16(gsA1, sm + aoff + 1024);
#pragma unroll
    for (int c = 0; c < 4; ++c)
        gll16(w1g + boff + c * 1024 + (lane << 4), sm + 16384 + boff + c * 1024);
    __syncthreads();

#pragma unroll
    for (int kt = 0; kt < 16; ++kt) {
        // issue next K-step's staging (DMA, no VGPRs -> cannot be sunk)
        if (kt < 15) {
            int ktn = kt + 1;
            char* An = sm + (ktn & 1) * 8192;
            char* Bn = sm + 16384 + (ktn & 1) * 16384;
            gll16(gsA0 + ktn * 32, An + aoff);
            gll16(gsA1 + ktn * 32, An + aoff + 1024);
#pragma unroll
            for (int c = 0; c < 4; ++c)
                gll16(w1g + ktn * 16384 + boff + c * 1024 + (lane << 4),
                      Bn + boff + c * 1024);
        }
        // compute from current buffers
        const char* Ac = sm + (kt & 1) * 8192;
        const char* Bc = sm + 16384 + (kt & 1) * 16384;
        bf16x8 Af[2];
#pragma unroll
        for (int mf = 0; mf < 2; ++mf) {
            int rowIdx = wm * 32 + mf * 16 + l15;
            int sw = (rowIdx & 3) << 1;
            const char* pa = Ac + rowIdx * 128 + (((2 * lg) ^ sw) << 4);
            float4 fa = *(const float4*)pa;
            float4 fb = *(const float4*)(pa + 16);
            Af[mf] = mk8(pk2t(fa.x, fa.y), pk2t(fa.z, fa.w),
                         pk2t(fb.x, fb.y), pk2t(fb.z, fb.w));
        }
#pragma unroll
        for (int nf = 0; nf < 8; ++nf) {
            bf16x8 B = *(const bf16x8*)(Bc + (wn * 128 + nf * 16 + l15) * 64 + lg * 16);
            acc[0][nf] = __builtin_amdgcn_mfma_f32_16x16x32_bf16(Af[0], B, acc[0][nf], 0, 0, 0);
            acc[1][nf] = __builtin_amdgcn_mfma_f32_16x16x32_bf16(Af[1], B, acc[1][nf], 0, 0, 0);
        }
        __syncthreads();        // drains next-step DMA; buffers swap safely
    }

    // ---- h1 = relu(acc+b1) -> bf16 -> LDS frag-linear image [0:32K) ----
    // element (row,col): g=row>>4, idx = ((ks*4+g)*64 + (row&15)*4 + lgw)*8 + j
    ushort* h1l = (ushort*)sm;
#pragma unroll
    for (int nf = 0; nf < 8; ++nf) {
        int col = wn * 128 + nf * 16 + l15;
        float bb = b1[col];
        int ks = col >> 5, lgw = (col >> 3) & 3, j = col & 7;
#pragma unroll
        for (int mf = 0; mf < 2; ++mf) {
            int g = wm * 2 + mf;
#pragma unroll
            for (int r = 0; r < 4; ++r) {
                float v = fmaxf(acc[mf][nf][r] + bb, 0.f);
                int l15w = lg * 4 + r;
                h1l[(((ks * 4 + g) * 64) + l15w * 4 + lgw) * 8 + j] = f2bf(v);
            }
        }
    }
    __syncthreads();

    // ---- phase 2: wave wid -> rows wid*16..+15, all 64 cols, K=256 ----
    f32x4 acc2[4];
#pragma unroll
    for (int i = 0; i < 4; ++i) acc2[i] = (f32x4)0.f;
#pragma unroll
    for (int ks = 0; ks < 8; ++ks) {
        bf16x8 A = *(const bf16x8*)&h1l[((ks * 4 + wid) * 64 + l15 * 4 + lg) * 8];
#pragma unroll
        for (int nf = 0; nf < 4; ++nf) {
            size_t bo = (size_t)ks * 2048 + (nf * 16 + l15) * 32 + (lg << 3);
            bf16x8 Bh = *(const bf16x8*)(w2h + bo);
            bf16x8 Bl = *(const bf16x8*)(w2l + bo);
            acc2[nf] = __builtin_amdgcn_mfma_f32_16x16x32_bf16(A, Bh, acc2[nf], 0, 0, 0);
            acc2[nf] = __builtin_amdgcn_mfma_f32_16x16x32_bf16(A, Bl, acc2[nf], 0, 0, 0);
        }
    }

    // ---- epilogue ----
    int flag1 = flags[1];
    float a0c = acoef[0];
    float z[4][4];
#pragma unroll
    for (int nf = 0; nf < 4; ++nf) {
        float bb = b2[nf * 16 + l15];
#pragma unroll
        for (int r = 0; r < 4; ++r) z[nf][r] = acc2[nf][r] + bb;
    }
    if (!flag1) {
        // fused log_softmax: the 16 l15-lanes of this lg group share 4 rows
#pragma unroll
        for (int r = 0; r < 4; ++r) {
            int row = row0 + wid * 16 + lg * 4 + r;
            float mx = fmaxf(fmaxf(z[0][r], z[1][r]), fmaxf(z[2][r], z[3][r]));
#pragma unroll
            for (int off = 1; off < 16; off <<= 1) mx = fmaxf(mx, __shfl_xor(mx, off, 64));
            float s = expf(z[0][r] - mx) + expf(z[1][r] - mx)
                    + expf(z[2][r] - mx) + expf(z[3][r] - mx);
#pragma unroll
            for (int off = 1; off < 16; off <<= 1) s += __shfl_xor(s, off, 64);
            float lns = logf(s);
            if (row < N) {
#pragma unroll
                for (int nf = 0; nf < 4; ++nf)
                    out[(size_t)row * 64 + nf * 16 + l15] = z[nf][r] - mx - lns;
            }
        }
    } else {
#pragma unroll
        for (int nf = 0; nf < 4; ++nf) {
            int col = nf * 16 + l15;
#pragma unroll
            for (int r = 0; r < 4; ++r) {
                int row = row0 + wid * 16 + lg * 4 + r;
                if (row < N) {
                    size_t o = (size_t)row * 64 + col;
                    v0[o] = z[nf][r];
                    out[o] = a0c * z[nf][r];
                }
            }
        }
    }
}

// ---- all graph work in one cooperative kernel (active path only) ----------
__global__ __launch_bounds__(256) void graph_coop(
    const int* __restrict__ src, const int* __restrict__ dst, int E, int N,
    int* __restrict__ degs, int* __restrict__ degd, int* __restrict__ cursor,
    int* __restrict__ rowp, int* __restrict__ csrs, float* __restrict__ csrw,
    float* __restrict__ v0, float* __restrict__ v1, float* __restrict__ out,
    const float* __restrict__ acoef, const int* __restrict__ flags)
{
    __shared__ int sums[256];
    if (!flags[1]) return;                  // uniform early-out: no syncs occur
    cg::grid_group grid = cg::this_grid();
    int gtid = blockIdx.x * 256 + threadIdx.x;
    int gstr = gridDim.x * 256;

    for (int i = gtid; i < N; i += gstr) { degs[i] = 0; degd[i] = 0; cursor[i] = 0; }
    grid.sync();
    for (int e = gtid; e < E; e += gstr) {
        atomicAdd(&degs[src[e]], 1);
        atomicAdd(&degd[dst[e]], 1);
    }
    grid.sync();
    if (blockIdx.x == 0) {
        int tid = threadIdx.x;
        int chunk = (N + 255) / 256;
        int s0 = tid * chunk;
        int s1 = s0 + chunk; if (s1 > N) s1 = N; if (s0 > N) s0 = N;
        int s = 0;
        for (int i = s0; i < s1; ++i) s += degd[i];
        sums[tid] = s;
        __syncthreads();
        for (int off = 1; off < 256; off <<= 1) {
            int v = (tid >= off) ? sums[tid - off] : 0;
            __syncthreads();
            sums[tid] += v;
            __syncthreads();
        }
        int run = sums[tid] - s;
        for (int i = s0; i < s1; ++i) { rowp[i] = run; run += degd[i]; }
        if (tid == 255) rowp[N] = sums[255];
    }
    grid.sync();
    for (int e = gtid; e < E; e += gstr) {
        int s = src[e], d = dst[e];
        int dgs = degs[s], dgd = degs[d];
        float ws_ = (dgs > 0 ? rsqrtf((float)dgs) : 0.f)
                  * (dgd > 0 ? rsqrtf((float)dgd) : 0.f);
        int slot = rowp[d] + atomicAdd(&cursor[d], 1);
        csrs[slot] = s;
        csrw[slot] = ws_;
    }
    grid.sync();
    const float* va = v0;
    float* vb = v1;
    int lane = threadIdx.x & 63;
    int grpbase = lane & 48;
    for (int j = 1; j <= KORD; ++j) {
        if (!flags[j]) break;               // uniform
        float aj = acoef[j];
        for (int idx = gtid; idx < N * 16; idx += gstr) {
            int n = idx >> 4;
            int q = idx & 15;
            int beg = rowp[n], end = rowp[n + 1];
            float4 acc = make_float4(0.f, 0.f, 0.f, 0.f);
            for (int base = beg; base < end; base += 16) {
                int s = 0; float wvv = 0.f;
                int ii = base + q;
                if (ii < end) { s = csrs[ii]; wvv = csrw[ii]; }
                int m = end - base; if (m > 16) m = 16;
                for (int u = 0; u < m; ++u) {
                    int ss = __shfl(s, grpbase + u, 64);
                    float ww = __shfl(wvv, grpbase + u, 64);
                    float4 vv = *(const float4*)(va + ((long)ss << 6) + (q << 2));
                    acc.x += ww * vv.x; acc.y += ww * vv.y;
                    acc.z += ww * vv.z; acc.w += ww * vv.w;
                }
            }
            long o = ((long)n << 6) + (q << 2);
            *(float4*)(vb + o) = acc;
            float4 ov = *(const float4*)(out + o);
            ov.x += aj * acc.x; ov.y += aj * acc.y;
            ov.z += aj * acc.z; ov.w += aj * acc.w;
            *(float4*)(out + o) = ov;
        }
        grid.sync();
        float* tsw = vb; vb = (float*)va; va = tsw;
    }
    for (int idx = gtid; idx < N * 64; idx += gstr) {
        int n = idx >> 6;
        int c = idx & 63;
        float v = out[(long)n * 64 + c];
        float mx = v;
#pragma unroll
        for (int off = 32; off; off >>= 1) mx = fmaxf(mx, __shfl_xor(mx, off, 64));
        float e = expf(v - mx);
        float s = e;
#pragma unroll
        for (int off = 32; off; off >>= 1) s += __shfl_xor(s, off, 64);
        out[(long)n * 64 + c] = v - mx - logf(s);
    }
}

extern "C" void kernel_launch(void* const* d_in, const int* in_sizes, int n_in,
                              void* d_out, int out_size, void* d_ws, size_t ws_size,
                              hipStream_t stream)
{
    const float* x    = (const float*)d_in[0];
    const int*   ei   = (const int*)d_in[1];
    const float* W1   = (const float*)d_in[2];
    const float* b1   = (const float*)d_in[3];
    const float* W2   = (const float*)d_in[4];
    const float* b2   = (const float*)d_in[5];
    const float* temp = (const float*)d_in[6];

    int N = in_sizes[0] / 512;
    int E = in_sizes[1] / 2;
    const int* src = ei;
    const int* dst = ei + E;
    float* out = (float*)d_out;

    char* w = (char*)d_ws;
    auto alloc = [&](size_t bytes) {
        char* p = w;
        w += (bytes + 255) & ~(size_t)255;
        return p;
    };
    float* acoef  = (float*)alloc(64);
    int*   flags  = (int*)alloc(64);
    int*   degs   = (int*)alloc((size_t)N * 4);
    int*   degd   = (int*)alloc((size_t)N * 4);
    int*   cursor = (int*)alloc((size_t)N * 4);
    int*   rowp   = (int*)alloc((size_t)(N + 1) * 4);
    int*   csrs   = (int*)alloc((size_t)E * 4);
    float* csrw   = (float*)alloc((size_t)E * 4);
    ushort* w1b   = (ushort*)alloc(512 * 256 * 2);
    ushort* w2h   = (ushort*)alloc(256 * 64 * 2);
    ushort* w2l   = (ushort*)alloc(256 * 64 * 2);
    float* v0     = (float*)alloc((size_t)N * 64 * 4);
    float* v1     = (float*)alloc((size_t)N * 64 * 4);

    prep_all<<<576, 256, 0, stream>>>(temp, W1, W2, acoef, flags, w1b, w2h, w2l);

    int ntiles = (N + 63) / 64;
    mlp_kernel<<<ntiles, 256, 0, stream>>>(x, w1b, w2h, w2l, b1, b2, v0, out,
                                           acoef, flags, N);

    int Ei = E, Ni = N;
    void* cargs[] = {
        (void*)&src, (void*)&dst, (void*)&Ei, (void*)&Ni,
        (void*)&degs, (void*)&degd, (void*)&cursor, (void*)&rowp,
        (void*)&csrs, (void*)&csrw, (void*)&v0, (void*)&v1, (void*)&out,
        (void*)&acoef, (void*)&flags
    };
    hipLaunchCooperativeKernel((void*)graph_coop, dim3(1024), dim3(256),
                               cargs, 0, stream);
}